// Round 6
// baseline (186.972 us; speedup 1.0000x reference)
//
#include <hip/hip_runtime.h>
#include <hip/hip_bf16.h>
#include <cstdio>
#include <cstdint>

// Problem constants (B=2, S=4096, D=1024, E=8, K=2)
static constexpr int TOK = 8192;    // B*S tokens
static constexpr int DIM = 1024;    // model dim (in = out)
static constexpr int NEXP = 8;
static constexpr int NGRP = 16;     // (k, expert) groups

typedef unsigned short u16;
typedef unsigned int u32;

using floatx4 = __attribute__((ext_vector_type(4))) float;
using bf16x8  = __attribute__((ext_vector_type(8))) __bf16;

// meta (ints): [0..15] counts, [16..31] offsets, [48] numTiles, [49] numTiles k=0
// tileMap: up to 80 ints, (g<<12)|m0  (BM=256 tiles)

// ---------- helpers ----------
__device__ __forceinline__ u16 f2bf(float f) {
  union { float f; u32 u; } v; v.f = f;
  u32 r = v.u + 0x7fffu + ((v.u >> 16) & 1u);   // RNE
  return (u16)(r >> 16);
}

__device__ __forceinline__ float bf2f(u16 b) {
  union { u32 u; float f; } v; v.u = (u32)b << 16;
  return v.f;
}

__device__ __forceinline__ void gload_lds16(const void* g, void* l) {
  __builtin_amdgcn_global_load_lds(
      (const __attribute__((address_space(1))) void*)g,
      (__attribute__((address_space(3))) void*)l,
      16, 0, 0);
}

// ---------- fused bookkeeping (one block, parallel scan/fill) ----------
__global__ __launch_bounds__(1024)
void prep_kernel(const int* __restrict__ idx, const float* __restrict__ ew,
                 int* __restrict__ meta, int* __restrict__ tileMap,
                 int* __restrict__ tokList, float* __restrict__ wList,
                 int* __restrict__ posOf) {
  __shared__ int cnt[NGRP], offS[NGRP], cur[NGRP], tbase[NGRP];
  const int tid = threadIdx.x;            // 1024 threads, 16 items each
  if (tid < NGRP) cnt[tid] = 0;
  __syncthreads();
  int gl[16];
#pragma unroll
  for (int j = 0; j < 16; ++j) {
    int i = tid + 1024 * j;               // (token,k) flat: k = i&1
    int g = ((i & 1) << 3) | idx[i];
    gl[j] = g;
    atomicAdd(&cnt[g], 1);
  }
  __syncthreads();
  if (tid == 0) {                         // tiny 16-step scan
    int run = 0, t = 0, tk0 = 0;
    for (int g = 0; g < NGRP; ++g) {
      offS[g] = run; cur[g] = run; tbase[g] = t;
      t += (cnt[g] + 255) >> 8;           // tiles of BM=256
      if (g == NEXP - 1) tk0 = t;
      run += cnt[g];
    }
    meta[48] = t;
    meta[49] = tk0;
  }
  __syncthreads();
  if (tid < NGRP) {                       // parallel meta + tileMap fill
    meta[tid] = cnt[tid];
    meta[16 + tid] = offS[tid];
    int b = tbase[tid], n = (cnt[tid] + 255) >> 8;
    for (int m0 = 0; m0 < n; ++m0) tileMap[b + m0] = (tid << 12) | m0;
  }
#pragma unroll
  for (int j = 0; j < 16; ++j) {
    int i = tid + 1024 * j;
    int pos = atomicAdd(&cur[gl[j]], 1);
    tokList[pos] = i >> 1;
    wList[pos] = ew[i];
    posOf[i] = pos;
  }
}

// ---------- gather + convert: read each token row ONCE, write its 2 slots ----------
__global__ __launch_bounds__(256)
void gather_x_kernel(const float* __restrict__ x, const int* __restrict__ posOf,
                     u16* __restrict__ Abuf) {
  const int t = blockIdx.x, tid = threadIdx.x;
  float4 v = reinterpret_cast<const float4*>(x + ((size_t)t << 10))[tid];
  ushort4 o;
  o.x = f2bf(v.x); o.y = f2bf(v.y); o.z = f2bf(v.z); o.w = f2bf(v.w);
  const int p0 = posOf[2 * t], p1 = posOf[2 * t + 1];
  reinterpret_cast<ushort4*>(Abuf + ((size_t)p0 << 10))[tid] = o;
  reinterpret_cast<ushort4*>(Abuf + ((size_t)p1 << 10))[tid] = o;
}

// W[e][d][f] fp32 -> Wt[e][f][d] bf16 (LDS-tiled transpose)
__global__ void transpose_w_kernel(const float* __restrict__ W, u16* __restrict__ wt) {
  __shared__ u16 tile[32][33];
  const int e = blockIdx.z;
  const int f0 = blockIdx.x * 32, d0 = blockIdx.y * 32;
  const float* src = W + ((size_t)e << 20);
  u16* dst = wt + ((size_t)e << 20);
  const int tx = threadIdx.x, ty = threadIdx.y;   // 32 x 8
#pragma unroll
  for (int j = 0; j < 4; ++j) {
    int d = d0 + ty + 8 * j;
    tile[ty + 8 * j][tx] = f2bf(src[(size_t)d * DIM + f0 + tx]);
  }
  __syncthreads();
#pragma unroll
  for (int j = 0; j < 4; ++j) {
    int f = f0 + ty + 8 * j;
    dst[(size_t)f * DIM + d0 + tx] = tile[tx][ty + 8 * j];
  }
}

// ---------- grouped GEMM, 256x256x64, 8 waves, 4-phase/K-tile, LDS dbuf ----------
// pass = -1 : all 16 groups; k=0 -> out (fp32 store), k=1 -> cbuf (bf16 store).
// pass = 0  : k=0 groups, store to out.   pass = 1 : k=1 groups, out += (RMW).
__global__ __launch_bounds__(512, 2)
void moe_gemm_kernel(const u16* __restrict__ Abuf, const u16* __restrict__ wt,
                     const float* __restrict__ bias, const int* __restrict__ tokList,
                     const float* __restrict__ wList, const int* __restrict__ meta,
                     const int* __restrict__ tileMap, float* __restrict__ out,
                     u16* __restrict__ cbuf, int pass) {
  constexpr int BM = 256, BN = 256, BK = 64;
  constexpr int NKT = DIM / BK;                 // 16 K-tiles
  // XCD-bijective swizzle (nwg = gridDim.x*gridDim.y, divisible by 8)
  const int nwg = gridDim.x * gridDim.y;
  const int lin = blockIdx.y * gridDim.x + blockIdx.x;
  const int chunk = nwg >> 3;
  const int swz = (lin & 7) * chunk + (lin >> 3);
  int tileIdx = swz >> 2;                       // gridDim.x == 4
  const int nt = swz & 3;

  int tBase = 0, tEnd = meta[48];
  const int tilesK0 = meta[49];
  if (pass == 0) tEnd = tilesK0;
  else if (pass == 1) tBase = tilesK0;
  tileIdx += tBase;
  if (tileIdx >= tEnd) return;

  const int tm = tileMap[tileIdx];
  const int g = tm >> 12, m0 = tm & 0xfff;
  const int e = g & (NEXP - 1);
  const int nrem = meta[g] - m0 * BM;           // rows remaining in group (>0)
  const int listBase = meta[16 + g] + m0 * BM;

  __shared__ __align__(16) u16 As[2][BM * BK];  // 2 x 32KB
  __shared__ __align__(16) u16 Bs[2][BN * BK];  // 2 x 32KB  (total 128KB)

  const int tid = threadIdx.x;                  // 512 threads
  const int rowB = tid >> 3;                    // 0..63
  const int chnk = tid & 7;                     // 16B chunk in a 128B row
  const u16* wb = wt + ((size_t)e << 20);
  const u16* ab = Abuf + ((size_t)listBase << 10);   // contiguous sorted rows
  const size_t ntB = (size_t)nt * BN;

  const int wid = tid >> 6, lane = tid & 63;
  const int wm = (wid >> 2) * 128;              // 2 M-warps
  const int wn = (wid & 3) * 64;                // 4 N-warps
  const int lr = lane & 15, lg = lane >> 4;

  floatx4 acc[8][4];
#pragma unroll
  for (int i = 0; i < 8; ++i)
#pragma unroll
    for (int j = 0; j < 4; ++j) acc[i][j] = (floatx4){0.f, 0.f, 0.f, 0.f};

  // prologue: stage all 4 half-tiles of K-tile 0 into buffer 0
#pragma unroll
  for (int h = 0; h < 2; ++h)
#pragma unroll
    for (int r = 0; r < 2; ++r) {
      const int row = h * 128 + rowB + 64 * r;
      gload_lds16(ab + ((size_t)row << 10) + chnk * 8, &As[0][row * BK + chnk * 8]);
      gload_lds16(wb + ((ntB + row) << 10) + chnk * 8, &Bs[0][row * BK + chnk * 8]);
    }
  asm volatile("s_waitcnt vmcnt(0)" ::: "memory");
  __syncthreads();

  for (int kt = 0; kt < NKT; ++kt) {
    const int cb = kt & 1;
#pragma unroll
    for (int ph = 0; ph < 4; ++ph) {
      // stage one half-tile of K-tile kt+1 into buf cb^1 (disjoint from reads)
      if (kt < NKT - 1) {
        const int h = ph & 1;
        const size_t koff = (size_t)(kt + 1) * BK + chnk * 8;
        if (ph < 2) {
#pragma unroll
          for (int r = 0; r < 2; ++r) {
            const int row = h * 128 + rowB + 64 * r;
            gload_lds16(ab + ((size_t)row << 10) + koff, &As[cb ^ 1][row * BK + chnk * 8]);
          }
        } else {
#pragma unroll
          for (int r = 0; r < 2; ++r) {
            const int row = h * 128 + rowB + 64 * r;
            gload_lds16(wb + ((ntB + row) << 10) + koff, &Bs[cb ^ 1][row * BK + chnk * 8]);
          }
        }
      }
      // compute quadrant: mhalf = ph&1 (acc rows), ks = ph>>1 (K sub-step)
      const int ks = ph >> 1, mh = ph & 1;
      bf16x8 av[4], bv[4];
#pragma unroll
      for (int mi = 0; mi < 4; ++mi)
        av[mi] = *reinterpret_cast<const bf16x8*>(
            &As[cb][(wm + (mh * 4 + mi) * 16 + lr) * BK + ks * 32 + lg * 8]);
#pragma unroll
      for (int ni = 0; ni < 4; ++ni)
        bv[ni] = *reinterpret_cast<const bf16x8*>(
            &Bs[cb][(wn + ni * 16 + lr) * BK + ks * 32 + lg * 8]);
      __builtin_amdgcn_s_setprio(1);
#pragma unroll
      for (int mi = 0; mi < 4; ++mi)
#pragma unroll
        for (int ni = 0; ni < 4; ++ni)
          acc[mh * 4 + mi][ni] =
              __builtin_amdgcn_mfma_f32_16x16x32_bf16(av[mi], bv[ni], acc[mh * 4 + mi][ni], 0, 0, 0);
      __builtin_amdgcn_s_setprio(0);
    }
    asm volatile("s_waitcnt vmcnt(0)" ::: "memory");  // kt+1 fully landed
    __syncthreads();                                   // all waves done reading cb
  }

  // epilogue: D[row=(lane>>4)*4+r][col=lane&15] per 16x16 frag
  const bool toCbuf = (pass < 0) && (g >= NEXP);
  const bool rmw = (pass == 1);
  const float* bp = bias + e * DIM;
#pragma unroll
  for (int mi = 0; mi < 8; ++mi) {
#pragma unroll
    for (int r = 0; r < 4; ++r) {
      const int rl = wm + mi * 16 + lg * 4 + r;
      if (rl < nrem) {
        const int   tok = tokList[listBase + rl];
        const float w   = wList[listBase + rl];
        const size_t rowOff = (size_t)tok << 10;
#pragma unroll
        for (int ni = 0; ni < 4; ++ni) {
          const int col = nt * BN + wn + ni * 16 + lr;
          const float v = w * (acc[mi][ni][r] + bp[col]);
          if (toCbuf)      cbuf[rowOff + col] = f2bf(v);
          else if (rmw)    out[rowOff + col] += v;
          else             out[rowOff + col] = v;
        }
      }
    }
  }
}

// out += cbuf(bf16). 8.4M elems, 8 per thread.
__global__ __launch_bounds__(256)
void combine_kernel(float* __restrict__ out, const u16* __restrict__ cbuf) {
  const int p = blockIdx.x * 256 + threadIdx.x;   // 8-elem chunk index
  uint4 c = reinterpret_cast<const uint4*>(cbuf)[p];
  float4* o4 = reinterpret_cast<float4*>(out) + 2 * (size_t)p;
  float4 a = o4[0], b = o4[1];
  a.x += bf2f((u16)(c.x & 0xffff)); a.y += bf2f((u16)(c.x >> 16));
  a.z += bf2f((u16)(c.y & 0xffff)); a.w += bf2f((u16)(c.y >> 16));
  b.x += bf2f((u16)(c.z & 0xffff)); b.y += bf2f((u16)(c.z >> 16));
  b.z += bf2f((u16)(c.w & 0xffff)); b.w += bf2f((u16)(c.w >> 16));
  o4[0] = a; o4[1] = b;
}

// ---------- host ----------
extern "C" void kernel_launch(void* const* d_in, const int* in_sizes, int n_in,
                              void* d_out, int out_size, void* d_ws, size_t ws_size,
                              hipStream_t stream) {
  const float* x    = (const float*)d_in[0];   // [2,4096,1024] f32
  const float* ew   = (const float*)d_in[1];   // [2,4096,2]    f32
  const int*   idx  = (const int*)d_in[2];     // [2,4096,2]    i32
  const float* W    = (const float*)d_in[3];   // [8,1024,1024] f32
  const float* bias = (const float*)d_in[4];   // [8,1024]      f32
  float* out = (float*)d_out;                  // [2,4096,1024] f32

  char* ws = (char*)d_ws;
  u16*   Abuf = (u16*)ws;                                  // 32 MB sorted bf16 rows
  u16*   wtp  = (u16*)(ws + ((size_t)32 << 20));           // 16 MB bf16 W^T
  u16*   cbuf = (u16*)(ws + ((size_t)48 << 20));           // 16 MB bf16 k=1 partials (mode A)

  const size_t needB = ((size_t)48 << 20) + (194 << 10);   // no cbuf
  const size_t needA = ((size_t)64 << 20) + (194 << 10);   // with cbuf
  if (ws_size < needB) {
    fprintf(stderr, "kernel_launch: ws_size %zu < needed %zu\n", ws_size, needB);
    return;
  }
  const bool modeA = (ws_size >= needA);
  char* tail = ws + (modeA ? ((size_t)64 << 20) : ((size_t)48 << 20));
  int*   tokList = (int*)tail;                  // 64 KB
  float* wList   = (float*)(tail + (64 << 10)); // 64 KB
  int*   posOf   = (int*)(tail + (128 << 10));  // 64 KB
  int*   meta    = (int*)(tail + (192 << 10));  // 64 ints
  int*   tileMap = (int*)(tail + (193 << 10));  // 80 ints

  prep_kernel<<<1, 1024, 0, stream>>>(idx, ew, meta, tileMap, tokList, wList, posOf);
  gather_x_kernel<<<TOK, 256, 0, stream>>>(x, posOf, Abuf);
  transpose_w_kernel<<<dim3(32, 32, 8), dim3(32, 8), 0, stream>>>(W, wtp);

  if (modeA) {
    // max tiles = 16384/256 + 16 = 80; grid 4 x 80 = 320 blocks (%8 == 0)
    moe_gemm_kernel<<<dim3(4, 80), 512, 0, stream>>>(
        Abuf, wtp, bias, tokList, wList, meta, tileMap, out, cbuf, -1);
    combine_kernel<<<TOK * DIM / 8 / 256, 256, 0, stream>>>(out, cbuf);
  } else {
    // two compact passes (max 40 tiles per k-slot; 4 x 40 = 160 blocks, %8 == 0)
    moe_gemm_kernel<<<dim3(4, 40), 512, 0, stream>>>(
        Abuf, wtp, bias, tokList, wList, meta, tileMap, out, nullptr, 0);
    moe_gemm_kernel<<<dim3(4, 40), 512, 0, stream>>>(
        Abuf, wtp, bias, tokList, wList, meta, tileMap, out, nullptr, 1);
  }
}

// Round 7
// 123.433 us; speedup vs baseline: 1.5148x; 1.5148x over previous
//
#include <hip/hip_runtime.h>
#include <hip/hip_bf16.h>
#include <cstdio>
#include <cstdint>

// Problem constants (B=2, S=4096, D=1024, E=8, K=2)
static constexpr int TOK = 8192;    // B*S tokens
static constexpr int DIM = 1024;    // model dim (in = out)
static constexpr int NEXP = 8;
static constexpr int NGRP = 16;     // (k, expert) groups

typedef unsigned short u16;
typedef unsigned int u32;

using floatx4 = __attribute__((ext_vector_type(4))) float;
using bf16x8  = __attribute__((ext_vector_type(8))) __bf16;

// meta (ints): [0..15] counts, [16..31] offsets, [48] numTiles, [49] numTiles k=0
// tileMap: up to 144 ints, (g<<12)|m0  (BM=128 tiles)

// ---------- helpers ----------
__device__ __forceinline__ u16 f2bf(float f) {
  union { float f; u32 u; } v; v.f = f;
  u32 r = v.u + 0x7fffu + ((v.u >> 16) & 1u);   // RNE
  return (u16)(r >> 16);
}

__device__ __forceinline__ float bf2f(u16 b) {
  union { u32 u; float f; } v; v.u = (u32)b << 16;
  return v.f;
}

__device__ __forceinline__ void gload_lds16(const void* g, void* l) {
  __builtin_amdgcn_global_load_lds(
      (const __attribute__((address_space(1))) void*)g,
      (__attribute__((address_space(3))) void*)l,
      16, 0, 0);
}

// ---------- fused bookkeeping (one block, parallel scan/fill) ----------
__global__ __launch_bounds__(1024)
void prep_kernel(const int* __restrict__ idx, const float* __restrict__ ew,
                 int* __restrict__ meta, int* __restrict__ tileMap,
                 int* __restrict__ tokList, float* __restrict__ wList,
                 int* __restrict__ posOf) {
  __shared__ int cnt[NGRP], offS[NGRP], cur[NGRP], tbase[NGRP];
  const int tid = threadIdx.x;            // 1024 threads, 16 items each
  if (tid < NGRP) cnt[tid] = 0;
  __syncthreads();
  int gl[16];
#pragma unroll
  for (int j = 0; j < 16; ++j) {
    int i = tid + 1024 * j;               // (token,k) flat: k = i&1
    int g = ((i & 1) << 3) | idx[i];
    gl[j] = g;
    atomicAdd(&cnt[g], 1);
  }
  __syncthreads();
  if (tid == 0) {                         // tiny 16-step scan
    int run = 0, t = 0, tk0 = 0;
    for (int g = 0; g < NGRP; ++g) {
      offS[g] = run; cur[g] = run; tbase[g] = t;
      t += (cnt[g] + 127) >> 7;           // tiles of BM=128
      if (g == NEXP - 1) tk0 = t;
      run += cnt[g];
    }
    meta[48] = t;
    meta[49] = tk0;
  }
  __syncthreads();
  if (tid < NGRP) {                       // parallel meta + tileMap fill
    meta[tid] = cnt[tid];
    meta[16 + tid] = offS[tid];
    int b = tbase[tid], n = (cnt[tid] + 127) >> 7;
    for (int m0 = 0; m0 < n; ++m0) tileMap[b + m0] = (tid << 12) | m0;
  }
#pragma unroll
  for (int j = 0; j < 16; ++j) {
    int i = tid + 1024 * j;
    int pos = atomicAdd(&cur[gl[j]], 1);
    tokList[pos] = i >> 1;
    wList[pos] = ew[i];
    posOf[i] = pos;
  }
}

// ---------- gather + convert: read each token row ONCE, write its 2 slots ----------
__global__ __launch_bounds__(256)
void gather_x_kernel(const float* __restrict__ x, const int* __restrict__ posOf,
                     u16* __restrict__ Abuf) {
  const int t = blockIdx.x, tid = threadIdx.x;
  float4 v = reinterpret_cast<const float4*>(x + ((size_t)t << 10))[tid];
  ushort4 o;
  o.x = f2bf(v.x); o.y = f2bf(v.y); o.z = f2bf(v.z); o.w = f2bf(v.w);
  const int p0 = posOf[2 * t], p1 = posOf[2 * t + 1];
  reinterpret_cast<ushort4*>(Abuf + ((size_t)p0 << 10))[tid] = o;
  reinterpret_cast<ushort4*>(Abuf + ((size_t)p1 << 10))[tid] = o;
}

// W[e][d][f] fp32 -> Wt[e][f][d] bf16 (LDS-tiled transpose)
__global__ void transpose_w_kernel(const float* __restrict__ W, u16* __restrict__ wt) {
  __shared__ u16 tile[32][33];
  const int e = blockIdx.z;
  const int f0 = blockIdx.x * 32, d0 = blockIdx.y * 32;
  const float* src = W + ((size_t)e << 20);
  u16* dst = wt + ((size_t)e << 20);
  const int tx = threadIdx.x, ty = threadIdx.y;   // 32 x 8
#pragma unroll
  for (int j = 0; j < 4; ++j) {
    int d = d0 + ty + 8 * j;
    tile[ty + 8 * j][tx] = f2bf(src[(size_t)d * DIM + f0 + tx]);
  }
  __syncthreads();
#pragma unroll
  for (int j = 0; j < 4; ++j) {
    int f = f0 + ty + 8 * j;
    dst[(size_t)f * DIM + d0 + tx] = tile[tx][ty + 8 * j];
  }
}

// ---------- fused grouped GEMM, 128x128x64, serial single-buffer (r4 core) ----------
// T2 XOR-swizzle (both-sides, rule #21): LDS dest stays LINEAR (gload_lds
// requirement); the per-lane GLOBAL source chunk is pre-permuted
// cs = chnk ^ (row&7), and ds_read uses chunk (ks*4+lg) ^ (row&7).
// Read conflict drops from ~16-way (128B row stride, all lanes bank 0)
// to 2-way (free, m136).
// pass = -1 : all 16 groups; k=0 -> out (fp32 store), k=1 -> cbuf (bf16 store).
// pass = 0  : k=0 groups, store to out.   pass = 1 : k=1 groups, out += (RMW).
__global__ __launch_bounds__(256)
void moe_gemm_kernel(const u16* __restrict__ Abuf, const u16* __restrict__ wt,
                     const float* __restrict__ bias, const int* __restrict__ tokList,
                     const float* __restrict__ wList, const int* __restrict__ meta,
                     const int* __restrict__ tileMap, float* __restrict__ out,
                     u16* __restrict__ cbuf, int pass) {
  constexpr int BM = 128, BN = 128, BK = 64;
  // XCD mapping: nt == XCD id -> per-XCD B working set = 2 MB (L2-resident)
  const int chunk = gridDim.y;
  int lin = blockIdx.y * 8 + blockIdx.x;
  int swz = (lin & 7) * chunk + (lin >> 3);
  int tileIdx = swz >> 3, nt = swz & 7;

  int tBase = 0, tEnd = meta[48];
  const int tilesK0 = meta[49];
  if (pass == 0) tEnd = tilesK0;
  else if (pass == 1) tBase = tilesK0;
  tileIdx += tBase;
  if (tileIdx >= tEnd) return;

  const int tm = tileMap[tileIdx];
  const int g = tm >> 12, m0 = tm & 0xfff;
  const int e = g & (NEXP - 1);
  const int nrem = meta[g] - m0 * BM;          // rows remaining in group (>0)
  const int listBase = meta[16 + g] + m0 * BM;

  __shared__ __align__(16) u16 As[BM * BK];    // 16KB
  __shared__ __align__(16) u16 Bs[BN * BK];    // 16KB

  const int tid = threadIdx.x;
  const int rowA = tid >> 3;    // 0..31 (stride 32 over 4 rounds)
  const int chnk = tid & 7;     // 16B chunk slot in LDS (linear dest)
  const int csw  = chnk ^ (rowA & 7);   // pre-swizzled GLOBAL source chunk
  const u16* wb = wt + ((size_t)e << 20);
  const u16* ab = Abuf + ((size_t)listBase << 10);   // contiguous sorted rows

  const int wid = tid >> 6, lane = tid & 63;
  const int wm = (wid >> 1) * 64, wn = (wid & 1) * 64;   // 2x2 waves, 64x64 each
  const int lr = lane & 15, lg = lane >> 4;
  const int rx = lr & 7;        // read-side XOR key (= row&7 for all frag rows)

  floatx4 acc[4][4];
#pragma unroll
  for (int i = 0; i < 4; ++i)
#pragma unroll
    for (int j = 0; j < 4; ++j) acc[i][j] = (floatx4){0.f, 0.f, 0.f, 0.f};

  for (int kt = 0; kt < DIM / BK; ++kt) {
    __syncthreads();                      // previous tile fully consumed
#pragma unroll
    for (int r = 0; r < 4; ++r) {         // A: contiguous rows (source pre-swizzled)
      const int row = rowA + 32 * r;      // row&7 == rowA&7
      gload_lds16(ab + ((size_t)row << 10) + kt * BK + csw * 8,
                  &As[row * BK + chnk * 8]);
    }
#pragma unroll
    for (int r = 0; r < 4; ++r) {         // B: Wt rows (source pre-swizzled)
      const int row = rowA + 32 * r;
      gload_lds16(wb + ((size_t)(nt * BN + row) << 10) + kt * BK + csw * 8,
                  &Bs[row * BK + chnk * 8]);
    }
    asm volatile("s_waitcnt vmcnt(0)" ::: "memory");
    __syncthreads();

#pragma unroll
    for (int ks = 0; ks < 2; ++ks) {      // two K=32 sub-steps
      bf16x8 av[4], bv[4];
#pragma unroll
      for (int mi = 0; mi < 4; ++mi)
        av[mi] = *reinterpret_cast<const bf16x8*>(
            &As[(wm + mi * 16 + lr) * BK + (((ks * 4 + lg) ^ rx)) * 8]);
#pragma unroll
      for (int ni = 0; ni < 4; ++ni)
        bv[ni] = *reinterpret_cast<const bf16x8*>(
            &Bs[(wn + ni * 16 + lr) * BK + (((ks * 4 + lg) ^ rx)) * 8]);
#pragma unroll
      for (int mi = 0; mi < 4; ++mi)
#pragma unroll
        for (int ni = 0; ni < 4; ++ni)
          acc[mi][ni] = __builtin_amdgcn_mfma_f32_16x16x32_bf16(av[mi], bv[ni], acc[mi][ni], 0, 0, 0);
    }
  }

  // epilogue: D[row=(lane>>4)*4+r][col=lane&15] per 16x16 frag
  const bool toCbuf = (pass < 0) && (g >= NEXP);
  const bool rmw = (pass == 1);
  const float* bp = bias + e * DIM;
#pragma unroll
  for (int mi = 0; mi < 4; ++mi) {
#pragma unroll
    for (int r = 0; r < 4; ++r) {
      const int rl = wm + mi * 16 + lg * 4 + r;
      if (rl < nrem) {
        const int   tok = tokList[listBase + rl];
        const float w   = wList[listBase + rl];
        const size_t rowOff = (size_t)tok << 10;
#pragma unroll
        for (int ni = 0; ni < 4; ++ni) {
          const int col = nt * BN + wn + ni * 16 + lr;
          const float v = w * (acc[mi][ni][r] + bp[col]);
          if (toCbuf)      cbuf[rowOff + col] = f2bf(v);
          else if (rmw)    out[rowOff + col] += v;
          else             out[rowOff + col] = v;
        }
      }
    }
  }
}

// out += cbuf(bf16). 8.4M elems, 8 per thread.
__global__ __launch_bounds__(256)
void combine_kernel(float* __restrict__ out, const u16* __restrict__ cbuf) {
  const int p = blockIdx.x * 256 + threadIdx.x;   // 8-elem chunk index
  uint4 c = reinterpret_cast<const uint4*>(cbuf)[p];
  float4* o4 = reinterpret_cast<float4*>(out) + 2 * (size_t)p;
  float4 a = o4[0], b = o4[1];
  a.x += bf2f((u16)(c.x & 0xffff)); a.y += bf2f((u16)(c.x >> 16));
  a.z += bf2f((u16)(c.y & 0xffff)); a.w += bf2f((u16)(c.y >> 16));
  b.x += bf2f((u16)(c.z & 0xffff)); b.y += bf2f((u16)(c.z >> 16));
  b.z += bf2f((u16)(c.w & 0xffff)); b.w += bf2f((u16)(c.w >> 16));
  o4[0] = a; o4[1] = b;
}

// ---------- host ----------
extern "C" void kernel_launch(void* const* d_in, const int* in_sizes, int n_in,
                              void* d_out, int out_size, void* d_ws, size_t ws_size,
                              hipStream_t stream) {
  const float* x    = (const float*)d_in[0];   // [2,4096,1024] f32
  const float* ew   = (const float*)d_in[1];   // [2,4096,2]    f32
  const int*   idx  = (const int*)d_in[2];     // [2,4096,2]    i32
  const float* W    = (const float*)d_in[3];   // [8,1024,1024] f32
  const float* bias = (const float*)d_in[4];   // [8,1024]      f32
  float* out = (float*)d_out;                  // [2,4096,1024] f32

  char* ws = (char*)d_ws;
  u16*   Abuf = (u16*)ws;                                  // 32 MB sorted bf16 rows
  u16*   wtp  = (u16*)(ws + ((size_t)32 << 20));           // 16 MB bf16 W^T
  u16*   cbuf = (u16*)(ws + ((size_t)48 << 20));           // 16 MB bf16 k=1 partials (mode A)

  const size_t needB = ((size_t)48 << 20) + (194 << 10);   // no cbuf
  const size_t needA = ((size_t)64 << 20) + (194 << 10);   // with cbuf
  if (ws_size < needB) {
    fprintf(stderr, "kernel_launch: ws_size %zu < needed %zu\n", ws_size, needB);
    return;
  }
  const bool modeA = (ws_size >= needA);
  char* tail = ws + (modeA ? ((size_t)64 << 20) : ((size_t)48 << 20));
  int*   tokList = (int*)tail;                  // 64 KB
  float* wList   = (float*)(tail + (64 << 10)); // 64 KB
  int*   posOf   = (int*)(tail + (128 << 10));  // 64 KB
  int*   meta    = (int*)(tail + (192 << 10));  // 64 ints
  int*   tileMap = (int*)(tail + (193 << 10));  // 144 ints

  prep_kernel<<<1, 1024, 0, stream>>>(idx, ew, meta, tileMap, tokList, wList, posOf);
  gather_x_kernel<<<TOK, 256, 0, stream>>>(x, posOf, Abuf);
  transpose_w_kernel<<<dim3(32, 32, 8), dim3(32, 8), 0, stream>>>(W, wtp);

  if (modeA) {
    // max tiles = 16384/128 + 16 = 144; grid 8 x 144 (nwg %8 == 0)
    moe_gemm_kernel<<<dim3(8, 144), 256, 0, stream>>>(
        Abuf, wtp, bias, tokList, wList, meta, tileMap, out, cbuf, -1);
    combine_kernel<<<TOK * DIM / 8 / 256, 256, 0, stream>>>(out, cbuf);
  } else {
    moe_gemm_kernel<<<dim3(8, 72), 256, 0, stream>>>(
        Abuf, wtp, bias, tokList, wList, meta, tileMap, out, nullptr, 0);
    moe_gemm_kernel<<<dim3(8, 72), 256, 0, stream>>>(
        Abuf, wtp, bias, tokList, wList, meta, tileMap, out, nullptr, 1);
  }
}

// Round 8
// 118.922 us; speedup vs baseline: 1.5722x; 1.0379x over previous
//
#include <hip/hip_runtime.h>
#include <hip/hip_bf16.h>
#include <cstdio>
#include <cstdint>

// Problem constants (B=2, S=4096, D=1024, E=8, K=2)
static constexpr int TOK = 8192;    // B*S tokens
static constexpr int DIM = 1024;    // model dim (in = out)
static constexpr int NEXP = 8;
static constexpr int NGRP = 16;     // (k, expert) groups

typedef unsigned short u16;
typedef unsigned int u32;

using floatx4 = __attribute__((ext_vector_type(4))) float;
using bf16x8  = __attribute__((ext_vector_type(8))) __bf16;

// meta (ints): [0..15] counts, [16..31] offsets, [48] numTiles, [49] numTiles k=0
// tileMap: up to 144 ints, (g<<12)|m0  (BM=128 tiles)

// ---------- helpers ----------
__device__ __forceinline__ u16 f2bf(float f) {
  union { float f; u32 u; } v; v.f = f;
  u32 r = v.u + 0x7fffu + ((v.u >> 16) & 1u);   // RNE
  return (u16)(r >> 16);
}

__device__ __forceinline__ float bf2f(u16 b) {
  union { u32 u; float f; } v; v.u = (u32)b << 16;
  return v.f;
}

__device__ __forceinline__ void gload_lds16(const void* g, void* l) {
  __builtin_amdgcn_global_load_lds(
      (const __attribute__((address_space(1))) void*)g,
      (__attribute__((address_space(3))) void*)l,
      16, 0, 0);
}

// ---------- fused bookkeeping (one block, parallel scan/fill) ----------
__global__ __launch_bounds__(1024)
void prep_kernel(const int* __restrict__ idx, const float* __restrict__ ew,
                 int* __restrict__ meta, int* __restrict__ tileMap,
                 int* __restrict__ tokList, float* __restrict__ wList,
                 int* __restrict__ posOf) {
  __shared__ int cnt[NGRP], offS[NGRP], cur[NGRP], tbase[NGRP];
  const int tid = threadIdx.x;            // 1024 threads, 16 items each
  if (tid < NGRP) cnt[tid] = 0;
  __syncthreads();
  int gl[16];
#pragma unroll
  for (int j = 0; j < 16; ++j) {
    int i = tid + 1024 * j;               // (token,k) flat: k = i&1
    int g = ((i & 1) << 3) | idx[i];
    gl[j] = g;
    atomicAdd(&cnt[g], 1);
  }
  __syncthreads();
  if (tid == 0) {                         // tiny 16-step scan
    int run = 0, t = 0, tk0 = 0;
    for (int g = 0; g < NGRP; ++g) {
      offS[g] = run; cur[g] = run; tbase[g] = t;
      t += (cnt[g] + 127) >> 7;           // tiles of BM=128
      if (g == NEXP - 1) tk0 = t;
      run += cnt[g];
    }
    meta[48] = t;
    meta[49] = tk0;
  }
  __syncthreads();
  if (tid < NGRP) {                       // parallel meta + tileMap fill
    meta[tid] = cnt[tid];
    meta[16 + tid] = offS[tid];
    int b = tbase[tid], n = (cnt[tid] + 127) >> 7;
    for (int m0 = 0; m0 < n; ++m0) tileMap[b + m0] = (tid << 12) | m0;
  }
#pragma unroll
  for (int j = 0; j < 16; ++j) {
    int i = tid + 1024 * j;
    int pos = atomicAdd(&cur[gl[j]], 1);
    tokList[pos] = i >> 1;
    wList[pos] = ew[i];
    posOf[i] = pos;
  }
}

// ---------- fused setup: gather(x->Abuf, 2 slots) + transpose(W->Wt) ----------
// blocks [0, TOK)           : gather token row, write its 2 group slots
// blocks [TOK, TOK+8192)    : 32x32 transpose tile of one expert's W
__global__ __launch_bounds__(256)
void setup_kernel(const float* __restrict__ x, const int* __restrict__ posOf,
                  u16* __restrict__ Abuf, const float* __restrict__ W,
                  u16* __restrict__ wt) {
  const int bid = blockIdx.x;
  const int tid = threadIdx.x;
  if (bid < TOK) {
    const int t = bid;
    float4 v = reinterpret_cast<const float4*>(x + ((size_t)t << 10))[tid];
    ushort4 o;
    o.x = f2bf(v.x); o.y = f2bf(v.y); o.z = f2bf(v.z); o.w = f2bf(v.w);
    const int p0 = posOf[2 * t], p1 = posOf[2 * t + 1];
    reinterpret_cast<ushort4*>(Abuf + ((size_t)p0 << 10))[tid] = o;
    reinterpret_cast<ushort4*>(Abuf + ((size_t)p1 << 10))[tid] = o;
  } else {
    __shared__ u16 tile[32][33];
    const int b = bid - TOK;              // 0..8191
    const int e = b >> 10;                // 1024 tiles per expert
    const int f0 = ((b >> 5) & 31) * 32, d0 = (b & 31) * 32;
    const float* src = W + ((size_t)e << 20);
    u16* dst = wt + ((size_t)e << 20);
    const int tx = tid & 31, ty = tid >> 5;   // 32 x 8
#pragma unroll
    for (int j = 0; j < 4; ++j) {
      int d = d0 + ty + 8 * j;
      tile[ty + 8 * j][tx] = f2bf(src[(size_t)d * DIM + f0 + tx]);
    }
    __syncthreads();
#pragma unroll
    for (int j = 0; j < 4; ++j) {
      int f = f0 + ty + 8 * j;
      dst[(size_t)f * DIM + d0 + tx] = tile[tx][ty + 8 * j];
    }
  }
}

// ---------- fused grouped GEMM, 128x128x64, serial single-buffer, T2 swizzle ----------
// T2 XOR-swizzle (both-sides, rule #21): LDS dest stays LINEAR (gload_lds
// requirement); global source chunk pre-permuted cs = chnk ^ (row&7); ds_read
// uses chunk (ks*4+lg) ^ (row&7). Verified r7: SQ_LDS_BANK_CONFLICT == 0.
// __launch_bounds__(256,4): 4 waves/EU -> 4 blocks/CU (reg budget 128/thread;
// acc=64 AGPR + av/bv 32 VGPR + addressing ~20 should fit).
// pass = -1 : all 16 groups; k=0 -> out (fp32 store), k=1 -> cbuf (bf16 store).
// pass = 0  : k=0 groups, store to out.   pass = 1 : k=1 groups, out += (RMW).
__global__ __launch_bounds__(256, 4)
void moe_gemm_kernel(const u16* __restrict__ Abuf, const u16* __restrict__ wt,
                     const float* __restrict__ bias, const int* __restrict__ tokList,
                     const float* __restrict__ wList, const int* __restrict__ meta,
                     const int* __restrict__ tileMap, float* __restrict__ out,
                     u16* __restrict__ cbuf, int pass) {
  constexpr int BM = 128, BN = 128, BK = 64;
  // XCD mapping: nt == XCD id -> per-XCD B working set = 2 MB (L2-resident)
  const int chunk = gridDim.y;
  int lin = blockIdx.y * 8 + blockIdx.x;
  int swz = (lin & 7) * chunk + (lin >> 3);
  int tileIdx = swz >> 3, nt = swz & 7;

  int tBase = 0, tEnd = meta[48];
  const int tilesK0 = meta[49];
  if (pass == 0) tEnd = tilesK0;
  else if (pass == 1) tBase = tilesK0;
  tileIdx += tBase;
  if (tileIdx >= tEnd) return;

  const int tm = tileMap[tileIdx];
  const int g = tm >> 12, m0 = tm & 0xfff;
  const int e = g & (NEXP - 1);
  const int nrem = meta[g] - m0 * BM;          // rows remaining in group (>0)
  const int listBase = meta[16 + g] + m0 * BM;

  __shared__ __align__(16) u16 As[BM * BK];    // 16KB
  __shared__ __align__(16) u16 Bs[BN * BK];    // 16KB

  const int tid = threadIdx.x;
  const int rowA = tid >> 3;    // 0..31 (stride 32 over 4 rounds)
  const int chnk = tid & 7;     // 16B chunk slot in LDS (linear dest)
  const int csw  = chnk ^ (rowA & 7);   // pre-swizzled GLOBAL source chunk
  const u16* wb = wt + ((size_t)e << 20);
  const u16* ab = Abuf + ((size_t)listBase << 10);   // contiguous sorted rows

  const int wid = tid >> 6, lane = tid & 63;
  const int wm = (wid >> 1) * 64, wn = (wid & 1) * 64;   // 2x2 waves, 64x64 each
  const int lr = lane & 15, lg = lane >> 4;
  const int rx = lr & 7;        // read-side XOR key (= row&7 for all frag rows)

  floatx4 acc[4][4];
#pragma unroll
  for (int i = 0; i < 4; ++i)
#pragma unroll
    for (int j = 0; j < 4; ++j) acc[i][j] = (floatx4){0.f, 0.f, 0.f, 0.f};

  for (int kt = 0; kt < DIM / BK; ++kt) {
    __syncthreads();                      // previous tile fully consumed
#pragma unroll
    for (int r = 0; r < 4; ++r) {         // A: contiguous rows (source pre-swizzled)
      const int row = rowA + 32 * r;      // row&7 == rowA&7
      gload_lds16(ab + ((size_t)row << 10) + kt * BK + csw * 8,
                  &As[row * BK + chnk * 8]);
    }
#pragma unroll
    for (int r = 0; r < 4; ++r) {         // B: Wt rows (source pre-swizzled)
      const int row = rowA + 32 * r;
      gload_lds16(wb + ((size_t)(nt * BN + row) << 10) + kt * BK + csw * 8,
                  &Bs[row * BK + chnk * 8]);
    }
    asm volatile("s_waitcnt vmcnt(0)" ::: "memory");
    __syncthreads();

#pragma unroll
    for (int ks = 0; ks < 2; ++ks) {      // two K=32 sub-steps
      bf16x8 av[4], bv[4];
#pragma unroll
      for (int mi = 0; mi < 4; ++mi)
        av[mi] = *reinterpret_cast<const bf16x8*>(
            &As[(wm + mi * 16 + lr) * BK + (((ks * 4 + lg) ^ rx)) * 8]);
#pragma unroll
      for (int ni = 0; ni < 4; ++ni)
        bv[ni] = *reinterpret_cast<const bf16x8*>(
            &Bs[(wn + ni * 16 + lr) * BK + (((ks * 4 + lg) ^ rx)) * 8]);
#pragma unroll
      for (int mi = 0; mi < 4; ++mi)
#pragma unroll
        for (int ni = 0; ni < 4; ++ni)
          acc[mi][ni] = __builtin_amdgcn_mfma_f32_16x16x32_bf16(av[mi], bv[ni], acc[mi][ni], 0, 0, 0);
    }
  }

  // epilogue: D[row=(lane>>4)*4+r][col=lane&15] per 16x16 frag
  const bool toCbuf = (pass < 0) && (g >= NEXP);
  const bool rmw = (pass == 1);
  const float* bp = bias + e * DIM;
#pragma unroll
  for (int mi = 0; mi < 4; ++mi) {
#pragma unroll
    for (int r = 0; r < 4; ++r) {
      const int rl = wm + mi * 16 + lg * 4 + r;
      if (rl < nrem) {
        const int   tok = tokList[listBase + rl];
        const float w   = wList[listBase + rl];
        const size_t rowOff = (size_t)tok << 10;
#pragma unroll
        for (int ni = 0; ni < 4; ++ni) {
          const int col = nt * BN + wn + ni * 16 + lr;
          const float v = w * (acc[mi][ni][r] + bp[col]);
          if (toCbuf)      cbuf[rowOff + col] = f2bf(v);
          else if (rmw)    out[rowOff + col] += v;
          else             out[rowOff + col] = v;
        }
      }
    }
  }
}

// out += cbuf(bf16). 8.4M elems, 8 per thread.
__global__ __launch_bounds__(256)
void combine_kernel(float* __restrict__ out, const u16* __restrict__ cbuf) {
  const int p = blockIdx.x * 256 + threadIdx.x;   // 8-elem chunk index
  uint4 c = reinterpret_cast<const uint4*>(cbuf)[p];
  float4* o4 = reinterpret_cast<float4*>(out) + 2 * (size_t)p;
  float4 a = o4[0], b = o4[1];
  a.x += bf2f((u16)(c.x & 0xffff)); a.y += bf2f((u16)(c.x >> 16));
  a.z += bf2f((u16)(c.y & 0xffff)); a.w += bf2f((u16)(c.y >> 16));
  b.x += bf2f((u16)(c.z & 0xffff)); b.y += bf2f((u16)(c.z >> 16));
  b.z += bf2f((u16)(c.w & 0xffff)); b.w += bf2f((u16)(c.w >> 16));
  o4[0] = a; o4[1] = b;
}

// ---------- host ----------
extern "C" void kernel_launch(void* const* d_in, const int* in_sizes, int n_in,
                              void* d_out, int out_size, void* d_ws, size_t ws_size,
                              hipStream_t stream) {
  const float* x    = (const float*)d_in[0];   // [2,4096,1024] f32
  const float* ew   = (const float*)d_in[1];   // [2,4096,2]    f32
  const int*   idx  = (const int*)d_in[2];     // [2,4096,2]    i32
  const float* W    = (const float*)d_in[3];   // [8,1024,1024] f32
  const float* bias = (const float*)d_in[4];   // [8,1024]      f32
  float* out = (float*)d_out;                  // [2,4096,1024] f32

  char* ws = (char*)d_ws;
  u16*   Abuf = (u16*)ws;                                  // 32 MB sorted bf16 rows
  u16*   wtp  = (u16*)(ws + ((size_t)32 << 20));           // 16 MB bf16 W^T
  u16*   cbuf = (u16*)(ws + ((size_t)48 << 20));           // 16 MB bf16 k=1 partials (mode A)

  const size_t needB = ((size_t)48 << 20) + (194 << 10);   // no cbuf
  const size_t needA = ((size_t)64 << 20) + (194 << 10);   // with cbuf
  if (ws_size < needB) {
    fprintf(stderr, "kernel_launch: ws_size %zu < needed %zu\n", ws_size, needB);
    return;
  }
  const bool modeA = (ws_size >= needA);
  char* tail = ws + (modeA ? ((size_t)64 << 20) : ((size_t)48 << 20));
  int*   tokList = (int*)tail;                  // 64 KB
  float* wList   = (float*)(tail + (64 << 10)); // 64 KB
  int*   posOf   = (int*)(tail + (128 << 10));  // 64 KB
  int*   meta    = (int*)(tail + (192 << 10));  // 64 ints
  int*   tileMap = (int*)(tail + (193 << 10));  // 144 ints

  prep_kernel<<<1, 1024, 0, stream>>>(idx, ew, meta, tileMap, tokList, wList, posOf);
  setup_kernel<<<TOK + 8192, 256, 0, stream>>>(x, posOf, Abuf, W, wtp);

  if (modeA) {
    // max tiles = 16384/128 + 16 = 144; grid 8 x 144 (nwg %8 == 0)
    moe_gemm_kernel<<<dim3(8, 144), 256, 0, stream>>>(
        Abuf, wtp, bias, tokList, wList, meta, tileMap, out, cbuf, -1);
    combine_kernel<<<TOK * DIM / 8 / 256, 256, 0, stream>>>(out, cbuf);
  } else {
    moe_gemm_kernel<<<dim3(8, 72), 256, 0, stream>>>(
        Abuf, wtp, bias, tokList, wList, meta, tileMap, out, nullptr, 0);
    moe_gemm_kernel<<<dim3(8, 72), 256, 0, stream>>>(
        Abuf, wtp, bias, tokList, wList, meta, tileMap, out, nullptr, 1);
  }
}

// Round 9
// 116.523 us; speedup vs baseline: 1.6046x; 1.0206x over previous
//
#include <hip/hip_runtime.h>
#include <hip/hip_bf16.h>
#include <cstdio>
#include <cstdint>

// Problem constants (B=2, S=4096, D=1024, E=8, K=2)
static constexpr int TOK = 8192;    // B*S tokens
static constexpr int DIM = 1024;    // model dim (in = out)
static constexpr int NEXP = 8;
static constexpr int NGRP = 16;     // (k, expert) groups

typedef unsigned short u16;
typedef unsigned int u32;

using floatx4 = __attribute__((ext_vector_type(4))) float;
using bf16x8  = __attribute__((ext_vector_type(8))) __bf16;

// meta (ints): [0..15] counts, [16..31] offsets, [48] numTiles, [49] numTiles k=0
// tileMap: up to 144 ints, (g<<12)|m0  (BM=128 tiles)

// ---------- helpers ----------
__device__ __forceinline__ u16 f2bf(float f) {
  union { float f; u32 u; } v; v.f = f;
  u32 r = v.u + 0x7fffu + ((v.u >> 16) & 1u);   // RNE
  return (u16)(r >> 16);
}

__device__ __forceinline__ float bf2f(u16 b) {
  union { u32 u; float f; } v; v.u = (u32)b << 16;
  return v.f;
}

__device__ __forceinline__ void gload_lds16(const void* g, void* l) {
  __builtin_amdgcn_global_load_lds(
      (const __attribute__((address_space(1))) void*)g,
      (__attribute__((address_space(3))) void*)l,
      16, 0, 0);
}

// ---------- fused bookkeeping; per-wave counter replication (16x less LDS-atomic
// serialization than single counters) ----------
__global__ __launch_bounds__(1024)
void prep_kernel(const int* __restrict__ idx, const float* __restrict__ ew,
                 int* __restrict__ meta, int* __restrict__ tileMap,
                 int* __restrict__ tokList, float* __restrict__ wList,
                 int* __restrict__ posOf) {
  __shared__ int cnt2[16][NGRP];    // [wave][group]
  __shared__ int cur2[16][NGRP];    // per-wave scatter cursors
  __shared__ int tot[NGRP], offS[NGRP], tbase[NGRP];
  const int tid = threadIdx.x;      // 1024 threads, 16 items each
  const int wid = tid >> 6;
  if (tid < 16 * NGRP) ((int*)cnt2)[tid] = 0;
  __syncthreads();
  int gl[16];
#pragma unroll
  for (int j = 0; j < 16; ++j) {
    int i = tid + 1024 * j;         // (token,k) flat: k = i&1
    int g = ((i & 1) << 3) | idx[i];
    gl[j] = g;
    atomicAdd(&cnt2[wid][g], 1);
  }
  __syncthreads();
  if (tid < NGRP) {                 // column scan over waves for group `tid`
    int s = 0;
    for (int w = 0; w < 16; ++w) { cur2[w][tid] = s; s += cnt2[w][tid]; }
    tot[tid] = s;
  }
  __syncthreads();
  if (tid == 0) {                   // tiny 16-step group scan
    int run = 0, t = 0, tk0 = 0;
    for (int g = 0; g < NGRP; ++g) {
      offS[g] = run; tbase[g] = t;
      t += (tot[g] + 127) >> 7;     // tiles of BM=128
      if (g == NEXP - 1) tk0 = t;
      run += tot[g];
    }
    meta[48] = t;
    meta[49] = tk0;
  }
  __syncthreads();
  if (tid < NGRP) {                 // meta + tileMap fill
    meta[tid] = tot[tid];
    meta[16 + tid] = offS[tid];
    int b = tbase[tid], n = (tot[tid] + 127) >> 7;
    for (int m0 = 0; m0 < n; ++m0) tileMap[b + m0] = (tid << 12) | m0;
  }
  if (tid < 16 * NGRP) {            // rebase per-wave cursors to global offsets
    int w = tid >> 4, g = tid & 15;
    cur2[w][g] += offS[g];
  }
  __syncthreads();
#pragma unroll
  for (int j = 0; j < 16; ++j) {
    int i = tid + 1024 * j;
    int pos = atomicAdd(&cur2[wid][gl[j]], 1);
    tokList[pos] = i >> 1;
    wList[pos] = ew[i];
    posOf[i] = pos;
  }
}

// ---------- fused setup: gather(x->Abuf, 2 slots) + transpose(W->Wt) ----------
__global__ __launch_bounds__(256)
void setup_kernel(const float* __restrict__ x, const int* __restrict__ posOf,
                  u16* __restrict__ Abuf, const float* __restrict__ W,
                  u16* __restrict__ wt) {
  const int bid = blockIdx.x;
  const int tid = threadIdx.x;
  if (bid < TOK) {
    const int t = bid;
    float4 v = reinterpret_cast<const float4*>(x + ((size_t)t << 10))[tid];
    ushort4 o;
    o.x = f2bf(v.x); o.y = f2bf(v.y); o.z = f2bf(v.z); o.w = f2bf(v.w);
    const int p0 = posOf[2 * t], p1 = posOf[2 * t + 1];
    reinterpret_cast<ushort4*>(Abuf + ((size_t)p0 << 10))[tid] = o;
    reinterpret_cast<ushort4*>(Abuf + ((size_t)p1 << 10))[tid] = o;
  } else {
    __shared__ u16 tile[32][33];
    const int b = bid - TOK;              // 0..8191
    const int e = b >> 10;                // 1024 tiles per expert
    const int f0 = ((b >> 5) & 31) * 32, d0 = (b & 31) * 32;
    const float* src = W + ((size_t)e << 20);
    u16* dst = wt + ((size_t)e << 20);
    const int tx = tid & 31, ty = tid >> 5;   // 32 x 8
#pragma unroll
    for (int j = 0; j < 4; ++j) {
      int d = d0 + ty + 8 * j;
      tile[ty + 8 * j][tx] = f2bf(src[(size_t)d * DIM + f0 + tx]);
    }
    __syncthreads();
#pragma unroll
    for (int j = 0; j < 4; ++j) {
      int f = f0 + ty + 8 * j;
      dst[(size_t)f * DIM + d0 + tx] = tile[tx][ty + 8 * j];
    }
  }
}

// ---------- fused grouped GEMM, 128x128x64, serial single-buffer, T2 swizzle ----------
// mode 2 : all 16 groups; k=0 -> cbufA (bf16), k=1 -> cbufB (bf16). out untouched.
// mode 1 : all 16 groups; k=0 -> out (f32), k=1 -> cbufA (bf16).
// mode 0 / pass1 via tBase: two-pass fallback (store / RMW).
__global__ __launch_bounds__(256, 4)
void moe_gemm_kernel(const u16* __restrict__ Abuf, const u16* __restrict__ wt,
                     const float* __restrict__ bias, const int* __restrict__ tokList,
                     const float* __restrict__ wList, const int* __restrict__ meta,
                     const int* __restrict__ tileMap, float* __restrict__ out,
                     u16* __restrict__ cbufA, u16* __restrict__ cbufB, int mode,
                     int pass) {
  constexpr int BM = 128, BN = 128, BK = 64;
  // XCD mapping: nt == XCD id -> per-XCD B working set = 2 MB (L2-resident)
  const int chunk = gridDim.y;
  int lin = blockIdx.y * 8 + blockIdx.x;
  int swz = (lin & 7) * chunk + (lin >> 3);
  int tileIdx = swz >> 3, nt = swz & 7;

  int tBase = 0, tEnd = meta[48];
  const int tilesK0 = meta[49];
  if (mode == 0) { if (pass == 0) tEnd = tilesK0; else tBase = tilesK0; }
  tileIdx += tBase;
  if (tileIdx >= tEnd) return;

  const int tm = tileMap[tileIdx];
  const int g = tm >> 12, m0 = tm & 0xfff;
  const int e = g & (NEXP - 1);
  const int nrem = meta[g] - m0 * BM;          // rows remaining in group (>0)
  const int listBase = meta[16 + g] + m0 * BM;

  __shared__ __align__(16) u16 As[BM * BK];    // 16KB
  __shared__ __align__(16) u16 Bs[BN * BK];    // 16KB

  const int tid = threadIdx.x;
  const int rowA = tid >> 3;    // 0..31 (stride 32 over 4 rounds)
  const int chnk = tid & 7;     // 16B chunk slot in LDS (linear dest)
  const int csw  = chnk ^ (rowA & 7);   // pre-swizzled GLOBAL source chunk
  const u16* wb = wt + ((size_t)e << 20);
  const u16* ab = Abuf + ((size_t)listBase << 10);   // contiguous sorted rows

  const int wid = tid >> 6, lane = tid & 63;
  const int wm = (wid >> 1) * 64, wn = (wid & 1) * 64;   // 2x2 waves, 64x64 each
  const int lr = lane & 15, lg = lane >> 4;
  const int rx = lr & 7;        // read-side XOR key (= row&7 for all frag rows)

  floatx4 acc[4][4];
#pragma unroll
  for (int i = 0; i < 4; ++i)
#pragma unroll
    for (int j = 0; j < 4; ++j) acc[i][j] = (floatx4){0.f, 0.f, 0.f, 0.f};

  for (int kt = 0; kt < DIM / BK; ++kt) {
    __syncthreads();                      // previous tile fully consumed
#pragma unroll
    for (int r = 0; r < 4; ++r) {         // A: contiguous rows (source pre-swizzled)
      const int row = rowA + 32 * r;      // row&7 == rowA&7
      gload_lds16(ab + ((size_t)row << 10) + kt * BK + csw * 8,
                  &As[row * BK + chnk * 8]);
    }
#pragma unroll
    for (int r = 0; r < 4; ++r) {         // B: Wt rows (source pre-swizzled)
      const int row = rowA + 32 * r;
      gload_lds16(wb + ((size_t)(nt * BN + row) << 10) + kt * BK + csw * 8,
                  &Bs[row * BK + chnk * 8]);
    }
    asm volatile("s_waitcnt vmcnt(0)" ::: "memory");
    __syncthreads();

#pragma unroll
    for (int ks = 0; ks < 2; ++ks) {      // two K=32 sub-steps
      bf16x8 av[4], bv[4];
#pragma unroll
      for (int mi = 0; mi < 4; ++mi)
        av[mi] = *reinterpret_cast<const bf16x8*>(
            &As[(wm + mi * 16 + lr) * BK + (((ks * 4 + lg) ^ rx)) * 8]);
#pragma unroll
      for (int ni = 0; ni < 4; ++ni)
        bv[ni] = *reinterpret_cast<const bf16x8*>(
            &Bs[(wn + ni * 16 + lr) * BK + (((ks * 4 + lg) ^ rx)) * 8]);
#pragma unroll
      for (int mi = 0; mi < 4; ++mi)
#pragma unroll
        for (int ni = 0; ni < 4; ++ni)
          acc[mi][ni] = __builtin_amdgcn_mfma_f32_16x16x32_bf16(av[mi], bv[ni], acc[mi][ni], 0, 0, 0);
    }
  }

  // epilogue: D[row=(lane>>4)*4+r][col=lane&15] per 16x16 frag
  u16* cb = nullptr;
  bool rmw = false, f32out = false;
  if (mode == 2)      cb = (g < NEXP) ? cbufA : cbufB;
  else if (mode == 1) { if (g < NEXP) f32out = true; else cb = cbufA; }
  else                { f32out = true; rmw = (pass == 1); }
  const float* bp = bias + e * DIM;
#pragma unroll
  for (int mi = 0; mi < 4; ++mi) {
#pragma unroll
    for (int r = 0; r < 4; ++r) {
      const int rl = wm + mi * 16 + lg * 4 + r;
      if (rl < nrem) {
        const int   tok = tokList[listBase + rl];
        const float w   = wList[listBase + rl];
        const size_t rowOff = (size_t)tok << 10;
#pragma unroll
        for (int ni = 0; ni < 4; ++ni) {
          const int col = nt * BN + wn + ni * 16 + lr;
          const float v = w * (acc[mi][ni][r] + bp[col]);
          if (f32out) { if (rmw) out[rowOff + col] += v; else out[rowOff + col] = v; }
          else        cb[rowOff + col] = f2bf(v);
        }
      }
    }
  }
}

// out = cbufA + cbufB (both bf16). 8.4M elems, 8 per thread. No out-read.
__global__ __launch_bounds__(256)
void combine2_kernel(float* __restrict__ out, const u16* __restrict__ cbufA,
                     const u16* __restrict__ cbufB) {
  const int p = blockIdx.x * 256 + threadIdx.x;   // 8-elem chunk index
  uint4 ca = reinterpret_cast<const uint4*>(cbufA)[p];
  uint4 cb = reinterpret_cast<const uint4*>(cbufB)[p];
  float4 r0, r1;
  r0.x = bf2f((u16)(ca.x & 0xffff)) + bf2f((u16)(cb.x & 0xffff));
  r0.y = bf2f((u16)(ca.x >> 16))    + bf2f((u16)(cb.x >> 16));
  r0.z = bf2f((u16)(ca.y & 0xffff)) + bf2f((u16)(cb.y & 0xffff));
  r0.w = bf2f((u16)(ca.y >> 16))    + bf2f((u16)(cb.y >> 16));
  r1.x = bf2f((u16)(ca.z & 0xffff)) + bf2f((u16)(cb.z & 0xffff));
  r1.y = bf2f((u16)(ca.z >> 16))    + bf2f((u16)(cb.z >> 16));
  r1.z = bf2f((u16)(ca.w & 0xffff)) + bf2f((u16)(cb.w & 0xffff));
  r1.w = bf2f((u16)(ca.w >> 16))    + bf2f((u16)(cb.w >> 16));
  float4* o4 = reinterpret_cast<float4*>(out) + 2 * (size_t)p;
  o4[0] = r0; o4[1] = r1;
}

// out += cbuf(bf16) — r8 fallback path.
__global__ __launch_bounds__(256)
void combine_kernel(float* __restrict__ out, const u16* __restrict__ cbuf) {
  const int p = blockIdx.x * 256 + threadIdx.x;
  uint4 c = reinterpret_cast<const uint4*>(cbuf)[p];
  float4* o4 = reinterpret_cast<float4*>(out) + 2 * (size_t)p;
  float4 a = o4[0], b = o4[1];
  a.x += bf2f((u16)(c.x & 0xffff)); a.y += bf2f((u16)(c.x >> 16));
  a.z += bf2f((u16)(c.y & 0xffff)); a.w += bf2f((u16)(c.y >> 16));
  b.x += bf2f((u16)(c.z & 0xffff)); b.y += bf2f((u16)(c.z >> 16));
  b.z += bf2f((u16)(c.w & 0xffff)); b.w += bf2f((u16)(c.w >> 16));
  o4[0] = a; o4[1] = b;
}

// ---------- host ----------
extern "C" void kernel_launch(void* const* d_in, const int* in_sizes, int n_in,
                              void* d_out, int out_size, void* d_ws, size_t ws_size,
                              hipStream_t stream) {
  const float* x    = (const float*)d_in[0];   // [2,4096,1024] f32
  const float* ew   = (const float*)d_in[1];   // [2,4096,2]    f32
  const int*   idx  = (const int*)d_in[2];     // [2,4096,2]    i32
  const float* W    = (const float*)d_in[3];   // [8,1024,1024] f32
  const float* bias = (const float*)d_in[4];   // [8,1024]      f32
  float* out = (float*)d_out;                  // [2,4096,1024] f32

  char* ws = (char*)d_ws;
  u16*   Abuf  = (u16*)ws;                                 // 32 MB sorted bf16 rows
  u16*   wtp   = (u16*)(ws + ((size_t)32 << 20));          // 16 MB bf16 W^T
  u16*   cbufA = (u16*)(ws + ((size_t)48 << 20));          // 16 MB bf16 partials
  u16*   cbufB = (u16*)(ws + ((size_t)64 << 20));          // 16 MB bf16 partials (mode 2)

  const size_t tailSz = (size_t)(194 << 10);
  const size_t need0 = ((size_t)48 << 20) + tailSz;        // two-pass fallback
  const size_t need1 = ((size_t)64 << 20) + tailSz;        // single cbuf (r8)
  const size_t need2 = ((size_t)80 << 20) + tailSz;        // dual cbuf
  if (ws_size < need0) {
    fprintf(stderr, "kernel_launch: ws_size %zu < needed %zu\n", ws_size, need0);
    return;
  }
  const int mode = (ws_size >= need2) ? 2 : (ws_size >= need1) ? 1 : 0;
  char* tail = ws + ((mode == 2) ? ((size_t)80 << 20)
                                 : (mode == 1) ? ((size_t)64 << 20)
                                               : ((size_t)48 << 20));
  int*   tokList = (int*)tail;                  // 64 KB
  float* wList   = (float*)(tail + (64 << 10)); // 64 KB
  int*   posOf   = (int*)(tail + (128 << 10));  // 64 KB
  int*   meta    = (int*)(tail + (192 << 10));  // 64 ints
  int*   tileMap = (int*)(tail + (193 << 10));  // 144 ints

  prep_kernel<<<1, 1024, 0, stream>>>(idx, ew, meta, tileMap, tokList, wList, posOf);
  setup_kernel<<<TOK + 8192, 256, 0, stream>>>(x, posOf, Abuf, W, wtp);

  if (mode == 2) {
    moe_gemm_kernel<<<dim3(8, 144), 256, 0, stream>>>(
        Abuf, wtp, bias, tokList, wList, meta, tileMap, out, cbufA, cbufB, 2, 0);
    combine2_kernel<<<TOK * DIM / 8 / 256, 256, 0, stream>>>(out, cbufA, cbufB);
  } else if (mode == 1) {
    moe_gemm_kernel<<<dim3(8, 144), 256, 0, stream>>>(
        Abuf, wtp, bias, tokList, wList, meta, tileMap, out, cbufA, nullptr, 1, 0);
    combine_kernel<<<TOK * DIM / 8 / 256, 256, 0, stream>>>(out, cbufA);
  } else {
    moe_gemm_kernel<<<dim3(8, 72), 256, 0, stream>>>(
        Abuf, wtp, bias, tokList, wList, meta, tileMap, out, nullptr, nullptr, 0, 0);
    moe_gemm_kernel<<<dim3(8, 72), 256, 0, stream>>>(
        Abuf, wtp, bias, tokList, wList, meta, tileMap, out, nullptr, nullptr, 0, 1);
  }
}